// Round 1
// baseline (2273.134 us; speedup 1.0000x reference)
//
#include <hip/hip_runtime.h>
#include <math.h>

#define B_SZ 2
#define LSEQ 2048
#define DIMC 768
#define DIN 1536
#define DTR 48
#define DST 16
#define NROWS (B_SZ * LSEQ)

__device__ __forceinline__ float sigmoidf_(float x) { return 1.f / (1.f + expf(-x)); }

// ---------------- LayerNorm: one block per row (768 cols, 256 thr x 3) ---------
__global__ __launch_bounds__(256) void ln_kernel(const float* __restrict__ x,
                                                 const float* __restrict__ gamma,
                                                 const float* __restrict__ beta,
                                                 float* __restrict__ out) {
    int row = blockIdx.x;
    const float* xr = x + (size_t)row * DIMC;
    int t = threadIdx.x;
    float v0 = xr[t], v1 = xr[t + 256], v2 = xr[t + 512];
    float s = v0 + v1 + v2;
    float q = v0 * v0 + v1 * v1 + v2 * v2;
#pragma unroll
    for (int off = 32; off; off >>= 1) {
        s += __shfl_down(s, off);
        q += __shfl_down(q, off);
    }
    __shared__ float ls[4], lq[4];
    int wave = t >> 6, lane = t & 63;
    if (lane == 0) { ls[wave] = s; lq[wave] = q; }
    __syncthreads();
    float S = ls[0] + ls[1] + ls[2] + ls[3];
    float Q = lq[0] + lq[1] + lq[2] + lq[3];
    float mu = S * (1.f / DIMC);
    float var = Q * (1.f / DIMC) - mu * mu;
    float r = rsqrtf(var + 1e-5f);
    float* orow = out + (size_t)row * DIMC;
    orow[t]       = (v0 - mu) * r * gamma[t]       + beta[t];
    orow[t + 256] = (v1 - mu) * r * gamma[t + 256] + beta[t + 256];
    orow[t + 512] = (v2 - mu) * r * gamma[t + 512] + beta[t + 512];
}

// ---------------- Generic fp32 NT GEMM: C[M,N] = A[M,*lda] . W[N,K]^T --------
// EPI: 0 none, 1 softplus(acc + bias[col]), 2 acc + add[row*N+col]
// Tiles: 64x64, BK=16, 256 threads, 4x4 microtile. M must be mult of 64,
// K mult of 16; N guarded.
template <int EPI>
__global__ __launch_bounds__(256) void gemm_nt(const float* __restrict__ A, int lda,
                                               const float* __restrict__ W,
                                               const float* __restrict__ epi,
                                               float* __restrict__ C, int N, int K) {
    __shared__ float As[16][68];
    __shared__ float Bs[16][68];
    int bm = blockIdx.y * 64, bn = blockIdx.x * 64;
    int t = threadIdx.x;
    int lr = t >> 4, lc = t & 15;
    int am = t >> 2, ak = (t & 3) * 4;
    float acc[4][4];
#pragma unroll
    for (int i = 0; i < 4; i++)
#pragma unroll
        for (int j = 0; j < 4; j++) acc[i][j] = 0.f;

    for (int k0 = 0; k0 < K; k0 += 16) {
        float4 av = *reinterpret_cast<const float4*>(A + (size_t)(bm + am) * lda + k0 + ak);
        int wrow = bn + am;
        float4 wv = make_float4(0.f, 0.f, 0.f, 0.f);
        if (wrow < N) wv = *reinterpret_cast<const float4*>(W + (size_t)wrow * K + k0 + ak);
        As[ak + 0][am] = av.x; As[ak + 1][am] = av.y;
        As[ak + 2][am] = av.z; As[ak + 3][am] = av.w;
        Bs[ak + 0][am] = wv.x; Bs[ak + 1][am] = wv.y;
        Bs[ak + 2][am] = wv.z; Bs[ak + 3][am] = wv.w;
        __syncthreads();
#pragma unroll
        for (int k = 0; k < 16; ++k) {
            float a0 = As[k][lr * 4 + 0], a1 = As[k][lr * 4 + 1];
            float a2 = As[k][lr * 4 + 2], a3 = As[k][lr * 4 + 3];
            float b0 = Bs[k][lc * 4 + 0], b1 = Bs[k][lc * 4 + 1];
            float b2 = Bs[k][lc * 4 + 2], b3 = Bs[k][lc * 4 + 3];
            acc[0][0] += a0 * b0; acc[0][1] += a0 * b1; acc[0][2] += a0 * b2; acc[0][3] += a0 * b3;
            acc[1][0] += a1 * b0; acc[1][1] += a1 * b1; acc[1][2] += a1 * b2; acc[1][3] += a1 * b3;
            acc[2][0] += a2 * b0; acc[2][1] += a2 * b1; acc[2][2] += a2 * b2; acc[2][3] += a2 * b3;
            acc[3][0] += a3 * b0; acc[3][1] += a3 * b1; acc[3][2] += a3 * b2; acc[3][3] += a3 * b3;
        }
        __syncthreads();
    }
#pragma unroll
    for (int i = 0; i < 4; ++i) {
        int row = bm + lr * 4 + i;
        float* crow = C + (size_t)row * N;
#pragma unroll
        for (int j = 0; j < 4; ++j) {
            int col = bn + lc * 4 + j;
            if (col < N) {
                float v = acc[i][j];
                if (EPI == 1) {
                    v += epi[col];
                    v = (v > 20.f) ? v : log1pf(expf(v));
                } else if (EPI == 2) {
                    v += epi[(size_t)row * N + col];
                }
                crow[col] = v;
            }
        }
    }
}

// ---------------- depthwise causal conv (D_CONV=4) + SiLU --------------------
__global__ __launch_bounds__(256) void conv_silu(const float* __restrict__ xz,
                                                 const float* __restrict__ cw,
                                                 const float* __restrict__ cb,
                                                 float* __restrict__ u) {
    int d = blockIdx.x * 256 + threadIdx.x;  // 0..1535
    int row = blockIdx.y;                    // 0..4095 (b*L + l)
    int l = row & (LSEQ - 1);
    const float* base = xz + (size_t)row * (2 * DIN) + d;
    float w0 = cw[d * 4 + 0], w1 = cw[d * 4 + 1], w2 = cw[d * 4 + 2], w3 = cw[d * 4 + 3];
    float acc = cb[d];
    if (l >= 3) acc += base[-3 * 2 * DIN] * w0;
    if (l >= 2) acc += base[-2 * 2 * DIN] * w1;
    if (l >= 1) acc += base[-1 * 2 * DIN] * w2;
    acc += base[0] * w3;
    u[(size_t)row * DIN + d] = acc * sigmoidf_(acc);
}

// ---------------- selective scan: 16 lanes per (b,d) channel -----------------
// block = 256 thr = 16 channels; grid = B * DIN/16 = 192 blocks
__global__ __launch_bounds__(256) void scan_kernel(const float* __restrict__ u,
                                                   const float* __restrict__ delta,
                                                   const float* __restrict__ xdbl,
                                                   const float* __restrict__ xz,
                                                   const float* __restrict__ A_log,
                                                   const float* __restrict__ Dskip,
                                                   float* __restrict__ yg) {
    int blk = blockIdx.x;
    int b = blk / (DIN / 16);
    int d0 = (blk % (DIN / 16)) * 16;
    int t = threadIdx.x;
    int grp = t >> 4, s = t & 15;
    int d = d0 + grp;
    float Acoef = -expf(A_log[d * DST + s]);
    float Dv = Dskip[d];
    const float* ub = u + (size_t)b * LSEQ * DIN + d;
    const float* db = delta + (size_t)b * LSEQ * DIN + d;
    const float* xd = xdbl + (size_t)b * LSEQ * 80;
    const float* zb = xz + (size_t)b * LSEQ * (2 * DIN) + DIN + d;
    float* yb = yg + (size_t)b * LSEQ * DIN + d;
    float h = 0.f;
    for (int l = 0; l < LSEQ; ++l) {
        float dt = db[(size_t)l * DIN];
        float uu = ub[(size_t)l * DIN];
        float Bv = xd[l * 80 + DTR + s];
        float Cv = xd[l * 80 + DTR + DST + s];
        float dA = expf(dt * Acoef);
        h = h * dA + dt * uu * Bv;
        float c = h * Cv;
        c += __shfl_xor(c, 1);
        c += __shfl_xor(c, 2);
        c += __shfl_xor(c, 4);
        c += __shfl_xor(c, 8);
        if (s == 0) {
            float z = zb[(size_t)l * (2 * DIN)];
            float y = c + uu * Dv;
            yb[(size_t)l * DIN] = y * (z * sigmoidf_(z));
        }
    }
}

extern "C" void kernel_launch(void* const* d_in, const int* in_sizes, int n_in,
                              void* d_out, int out_size, void* d_ws, size_t ws_size,
                              hipStream_t stream) {
    const float* x    = (const float*)d_in[0];
    const float* lng  = (const float*)d_in[1];
    const float* lnb  = (const float*)d_in[2];
    const float* win  = (const float*)d_in[3];
    const float* cw   = (const float*)d_in[4];
    const float* cb   = (const float*)d_in[5];
    const float* wxp  = (const float*)d_in[6];
    const float* wdt  = (const float*)d_in[7];
    const float* bdt  = (const float*)d_in[8];
    const float* alog = (const float*)d_in[9];
    const float* dsk  = (const float*)d_in[10];
    const float* wout = (const float*)d_in[11];
    float* out = (float*)d_out;

    float* ws    = (float*)d_ws;
    float* h_ln  = ws;                                // 4096*768
    float* xz    = h_ln  + (size_t)NROWS * DIMC;      // 4096*3072
    float* u     = xz    + (size_t)NROWS * 2 * DIN;   // 4096*1536
    float* xdbl  = u     + (size_t)NROWS * DIN;       // 4096*80
    float* delta = xdbl  + (size_t)NROWS * 80;        // 4096*1536
    float* yg    = delta + (size_t)NROWS * DIN;       // 4096*1536

    ln_kernel<<<NROWS, 256, 0, stream>>>(x, lng, lnb, h_ln);
    gemm_nt<0><<<dim3(2 * DIN / 64, NROWS / 64), 256, 0, stream>>>(h_ln, DIMC, win, nullptr, xz, 2 * DIN, DIMC);
    conv_silu<<<dim3(DIN / 256, NROWS), 256, 0, stream>>>(xz, cw, cb, u);
    gemm_nt<0><<<dim3((80 + 63) / 64, NROWS / 64), 256, 0, stream>>>(u, DIN, wxp, nullptr, xdbl, 80, DIN);
    gemm_nt<1><<<dim3(DIN / 64, NROWS / 64), 256, 0, stream>>>(xdbl, 80, wdt, bdt, delta, DIN, DTR);
    scan_kernel<<<192, 256, 0, stream>>>(u, delta, xdbl, xz, alog, dsk, yg);
    gemm_nt<2><<<dim3(DIMC / 64, NROWS / 64), 256, 0, stream>>>(yg, DIN, wout, x, out, DIMC, DIN);
}

// Round 2
// 879.826 us; speedup vs baseline: 2.5836x; 2.5836x over previous
//
#include <hip/hip_runtime.h>
#include <math.h>

#define B_SZ 2
#define LSEQ 2048
#define DIMC 768
#define DIN 1536
#define DTR 48
#define DST 16
#define NROWS (B_SZ * LSEQ)
#define CHUNK 128
#define NCHUNK (LSEQ / CHUNK)   // 16
#define NGRP (DIN / 16)         // 96 channel-groups per batch

__device__ __forceinline__ float sigmoidf_(float x) { return 1.f / (1.f + __expf(-x)); }

// ---------------- LayerNorm: one block per row (768 cols, 256 thr x 3) ---------
__global__ __launch_bounds__(256) void ln_kernel(const float* __restrict__ x,
                                                 const float* __restrict__ gamma,
                                                 const float* __restrict__ beta,
                                                 float* __restrict__ out) {
    int row = blockIdx.x;
    const float* xr = x + (size_t)row * DIMC;
    int t = threadIdx.x;
    float v0 = xr[t], v1 = xr[t + 256], v2 = xr[t + 512];
    float s = v0 + v1 + v2;
    float q = v0 * v0 + v1 * v1 + v2 * v2;
#pragma unroll
    for (int off = 32; off; off >>= 1) {
        s += __shfl_down(s, off);
        q += __shfl_down(q, off);
    }
    __shared__ float ls[4], lq[4];
    int wave = t >> 6, lane = t & 63;
    if (lane == 0) { ls[wave] = s; lq[wave] = q; }
    __syncthreads();
    float S = ls[0] + ls[1] + ls[2] + ls[3];
    float Q = lq[0] + lq[1] + lq[2] + lq[3];
    float mu = S * (1.f / DIMC);
    float var = Q * (1.f / DIMC) - mu * mu;
    float r = rsqrtf(var + 1e-5f);
    float* orow = out + (size_t)row * DIMC;
    orow[t]       = (v0 - mu) * r * gamma[t]       + beta[t];
    orow[t + 256] = (v1 - mu) * r * gamma[t + 256] + beta[t + 256];
    orow[t + 512] = (v2 - mu) * r * gamma[t + 512] + beta[t + 512];
}

// ---------------- Generic fp32 NT GEMM: C[M,N] = A[M,*lda] . W[N,K]^T --------
template <int EPI>
__global__ __launch_bounds__(256) void gemm_nt(const float* __restrict__ A, int lda,
                                               const float* __restrict__ W,
                                               const float* __restrict__ epi,
                                               float* __restrict__ C, int N, int K) {
    __shared__ float As[16][68];
    __shared__ float Bs[16][68];
    int bm = blockIdx.y * 64, bn = blockIdx.x * 64;
    int t = threadIdx.x;
    int lr = t >> 4, lc = t & 15;
    int am = t >> 2, ak = (t & 3) * 4;
    float acc[4][4];
#pragma unroll
    for (int i = 0; i < 4; i++)
#pragma unroll
        for (int j = 0; j < 4; j++) acc[i][j] = 0.f;

    for (int k0 = 0; k0 < K; k0 += 16) {
        float4 av = *reinterpret_cast<const float4*>(A + (size_t)(bm + am) * lda + k0 + ak);
        int wrow = bn + am;
        float4 wv = make_float4(0.f, 0.f, 0.f, 0.f);
        if (wrow < N) wv = *reinterpret_cast<const float4*>(W + (size_t)wrow * K + k0 + ak);
        As[ak + 0][am] = av.x; As[ak + 1][am] = av.y;
        As[ak + 2][am] = av.z; As[ak + 3][am] = av.w;
        Bs[ak + 0][am] = wv.x; Bs[ak + 1][am] = wv.y;
        Bs[ak + 2][am] = wv.z; Bs[ak + 3][am] = wv.w;
        __syncthreads();
#pragma unroll
        for (int k = 0; k < 16; ++k) {
            float a0 = As[k][lr * 4 + 0], a1 = As[k][lr * 4 + 1];
            float a2 = As[k][lr * 4 + 2], a3 = As[k][lr * 4 + 3];
            float b0 = Bs[k][lc * 4 + 0], b1 = Bs[k][lc * 4 + 1];
            float b2 = Bs[k][lc * 4 + 2], b3 = Bs[k][lc * 4 + 3];
            acc[0][0] += a0 * b0; acc[0][1] += a0 * b1; acc[0][2] += a0 * b2; acc[0][3] += a0 * b3;
            acc[1][0] += a1 * b0; acc[1][1] += a1 * b1; acc[1][2] += a1 * b2; acc[1][3] += a1 * b3;
            acc[2][0] += a2 * b0; acc[2][1] += a2 * b1; acc[2][2] += a2 * b2; acc[2][3] += a2 * b3;
            acc[3][0] += a3 * b0; acc[3][1] += a3 * b1; acc[3][2] += a3 * b2; acc[3][3] += a3 * b3;
        }
        __syncthreads();
    }
#pragma unroll
    for (int i = 0; i < 4; ++i) {
        int row = bm + lr * 4 + i;
        float* crow = C + (size_t)row * N;
#pragma unroll
        for (int j = 0; j < 4; ++j) {
            int col = bn + lc * 4 + j;
            if (col < N) {
                float v = acc[i][j];
                if (EPI == 1) {
                    v += epi[col];
                    v = (v > 20.f) ? v : log1pf(__expf(v));
                } else if (EPI == 2) {
                    v += epi[(size_t)row * N + col];
                }
                crow[col] = v;
            }
        }
    }
}

// ---------------- depthwise causal conv (D_CONV=4) + SiLU --------------------
__global__ __launch_bounds__(256) void conv_silu(const float* __restrict__ xz,
                                                 const float* __restrict__ cw,
                                                 const float* __restrict__ cb,
                                                 float* __restrict__ u) {
    int d = blockIdx.x * 256 + threadIdx.x;  // 0..1535
    int row = blockIdx.y;                    // 0..4095 (b*L + l)
    int l = row & (LSEQ - 1);
    const float* base = xz + (size_t)row * (2 * DIN) + d;
    float w0 = cw[d * 4 + 0], w1 = cw[d * 4 + 1], w2 = cw[d * 4 + 2], w3 = cw[d * 4 + 3];
    float acc = cb[d];
    if (l >= 3) acc += base[-3 * 2 * DIN] * w0;
    if (l >= 2) acc += base[-2 * 2 * DIN] * w1;
    if (l >= 1) acc += base[-1 * 2 * DIN] * w2;
    acc += base[0] * w3;
    u[(size_t)row * DIN + d] = acc * sigmoidf_(acc);
}

// ---------------- chunked selective scan ------------------------------------
// Pass A: per-chunk local scan from h=0; emit h_end and P = prod(dA).
// Layout of hend/P/Hinit: [c][b][d][s]  (block writes 256 contiguous floats)
__global__ __launch_bounds__(256) void scan_partA(const float* __restrict__ u,
                                                  const float* __restrict__ delta,
                                                  const float* __restrict__ xdbl,
                                                  const float* __restrict__ A_log,
                                                  float* __restrict__ hend,
                                                  float* __restrict__ Pst) {
    int c = blockIdx.x;
    int bg = blockIdx.y;
    int b = bg / NGRP;
    int d0 = (bg % NGRP) * 16;
    int t = threadIdx.x;
    int grp = t >> 4, s = t & 15;
    int d = d0 + grp;
    float Acoef = -__expf(A_log[d * DST + s]);
    int l0 = c * CHUNK;
    const float* ub = u + ((size_t)b * LSEQ + l0) * DIN + d;
    const float* db = delta + ((size_t)b * LSEQ + l0) * DIN + d;
    const float* xd = xdbl + ((size_t)b * LSEQ + l0) * 80;
    float h = 0.f, P = 1.f;
    for (int l = 0; l < CHUNK; ++l) {
        float dt = db[(size_t)l * DIN];
        float uu = ub[(size_t)l * DIN];
        float Bv = xd[l * 80 + DTR + s];
        float dA = __expf(dt * Acoef);
        h = h * dA + dt * uu * Bv;
        P *= dA;
    }
    size_t idx = ((size_t)c * B_SZ + b) * (DIN * DST) + (size_t)d * DST + s;
    hend[idx] = h;
    Pst[idx] = P;
}

// Pass B: exclusive combine across chunks. tid = (b*DIN+d)*DST+s
__global__ __launch_bounds__(256) void scan_partB(const float* __restrict__ hend,
                                                  const float* __restrict__ Pst,
                                                  float* __restrict__ Hinit) {
    int tid = blockIdx.x * 256 + threadIdx.x;  // 0..49151
    float H = 0.f;
#pragma unroll
    for (int c = 0; c < NCHUNK; ++c) {
        size_t idx = (size_t)c * (B_SZ * DIN * DST) + tid;
        Hinit[idx] = H;
        H = Pst[idx] * H + hend[idx];
    }
}

// Pass C: re-run chunk with correct initial state, emit gated y.
__global__ __launch_bounds__(256) void scan_partC(const float* __restrict__ u,
                                                  const float* __restrict__ delta,
                                                  const float* __restrict__ xdbl,
                                                  const float* __restrict__ xz,
                                                  const float* __restrict__ A_log,
                                                  const float* __restrict__ Dskip,
                                                  const float* __restrict__ Hinit,
                                                  float* __restrict__ yg) {
    int c = blockIdx.x;
    int bg = blockIdx.y;
    int b = bg / NGRP;
    int d0 = (bg % NGRP) * 16;
    int t = threadIdx.x;
    int grp = t >> 4, s = t & 15;
    int d = d0 + grp;
    float Acoef = -__expf(A_log[d * DST + s]);
    float Dv = Dskip[d];
    int l0 = c * CHUNK;
    const float* ub = u + ((size_t)b * LSEQ + l0) * DIN + d;
    const float* db = delta + ((size_t)b * LSEQ + l0) * DIN + d;
    const float* xd = xdbl + ((size_t)b * LSEQ + l0) * 80;
    const float* zb = xz + ((size_t)b * LSEQ + l0) * (2 * DIN) + DIN + d;
    float* yb = yg + ((size_t)b * LSEQ + l0) * DIN + d;
    float h = Hinit[((size_t)c * B_SZ + b) * (DIN * DST) + (size_t)d * DST + s];
    for (int l = 0; l < CHUNK; ++l) {
        float dt = db[(size_t)l * DIN];
        float uu = ub[(size_t)l * DIN];
        float Bv = xd[l * 80 + DTR + s];
        float Cv = xd[l * 80 + DTR + DST + s];
        float dA = __expf(dt * Acoef);
        h = h * dA + dt * uu * Bv;
        float cc = h * Cv;
        cc += __shfl_xor(cc, 1);
        cc += __shfl_xor(cc, 2);
        cc += __shfl_xor(cc, 4);
        cc += __shfl_xor(cc, 8);
        if (s == 0) {
            float z = zb[(size_t)l * (2 * DIN)];
            float y = cc + uu * Dv;
            yb[(size_t)l * DIN] = y * (z * sigmoidf_(z));
        }
    }
}

extern "C" void kernel_launch(void* const* d_in, const int* in_sizes, int n_in,
                              void* d_out, int out_size, void* d_ws, size_t ws_size,
                              hipStream_t stream) {
    const float* x    = (const float*)d_in[0];
    const float* lng  = (const float*)d_in[1];
    const float* lnb  = (const float*)d_in[2];
    const float* win  = (const float*)d_in[3];
    const float* cw   = (const float*)d_in[4];
    const float* cb   = (const float*)d_in[5];
    const float* wxp  = (const float*)d_in[6];
    const float* wdt  = (const float*)d_in[7];
    const float* bdt  = (const float*)d_in[8];
    const float* alog = (const float*)d_in[9];
    const float* dsk  = (const float*)d_in[10];
    const float* wout = (const float*)d_in[11];
    float* out = (float*)d_out;

    float* ws    = (float*)d_ws;
    float* h_ln  = ws;                                // 4096*768 = 3.1M floats
    float* xz    = h_ln  + (size_t)NROWS * DIMC;      // 4096*3072
    float* u     = xz    + (size_t)NROWS * 2 * DIN;   // 4096*1536
    float* xdbl  = u     + (size_t)NROWS * DIN;       // 4096*80
    float* delta = xdbl  + (size_t)NROWS * 80;        // 4096*1536
    float* yg    = delta + (size_t)NROWS * DIN;       // 4096*1536
    // scan fix-up buffers reuse h_ln's space (dead after in_proj GEMM):
    // need 3 * NCHUNK*B*DIN*DST = 3*786432 floats < 4096*768 = 3.1M floats
    float* hend  = h_ln;                               // 786432
    float* Pst   = hend + (size_t)NCHUNK * B_SZ * DIN * DST;
    float* Hinit = Pst  + (size_t)NCHUNK * B_SZ * DIN * DST;

    ln_kernel<<<NROWS, 256, 0, stream>>>(x, lng, lnb, h_ln);
    gemm_nt<0><<<dim3(2 * DIN / 64, NROWS / 64), 256, 0, stream>>>(h_ln, DIMC, win, nullptr, xz, 2 * DIN, DIMC);
    conv_silu<<<dim3(DIN / 256, NROWS), 256, 0, stream>>>(xz, cw, cb, u);
    gemm_nt<0><<<dim3((80 + 63) / 64, NROWS / 64), 256, 0, stream>>>(u, DIN, wxp, nullptr, xdbl, 80, DIN);
    gemm_nt<1><<<dim3(DIN / 64, NROWS / 64), 256, 0, stream>>>(xdbl, 80, wdt, bdt, delta, DIN, DTR);
    scan_partA<<<dim3(NCHUNK, B_SZ * NGRP), 256, 0, stream>>>(u, delta, xdbl, alog, hend, Pst);
    scan_partB<<<B_SZ * DIN * DST / 256, 256, 0, stream>>>(hend, Pst, Hinit);
    scan_partC<<<dim3(NCHUNK, B_SZ * NGRP), 256, 0, stream>>>(u, delta, xdbl, xz, alog, dsk, Hinit, yg);
    gemm_nt<2><<<dim3(DIMC / 64, NROWS / 64), 256, 0, stream>>>(yg, DIN, wout, x, out, DIMC, DIN);
}

// Round 3
// 483.673 us; speedup vs baseline: 4.6997x; 1.8191x over previous
//
#include <hip/hip_runtime.h>
#include <math.h>

#define B_SZ 2
#define LSEQ 2048
#define DIMC 768
#define DIN 1536
#define DTR 48
#define DST 16
#define NROWS (B_SZ * LSEQ)
#define CHUNK 128
#define NCHUNK (LSEQ / CHUNK)   // 16
#define NGRP (DIN / 16)         // 96 channel-groups per batch

typedef __attribute__((ext_vector_type(8))) short short8;
typedef __attribute__((ext_vector_type(4))) float f32x4;
typedef unsigned short ushort;

__device__ __forceinline__ float sigmoidf_(float x) { return 1.f / (1.f + __expf(-x)); }

__device__ __forceinline__ ushort f2bf(float f) {
    union { float f; unsigned u; } v; v.f = f;
    unsigned r = v.u + 0x7FFFu + ((v.u >> 16) & 1u);
    return (ushort)(r >> 16);
}
__device__ __forceinline__ float bf2f(ushort h) {
    union { unsigned u; float f; } v; v.u = ((unsigned)h) << 16; return v.f;
}

// ---------------- weight fp32 -> bf16 conversion ----------------------------
__global__ __launch_bounds__(256) void cvt_bf16(const float* __restrict__ src,
                                                ushort* __restrict__ dst, int n) {
    int i = blockIdx.x * 256 + threadIdx.x;
    if (i < n) dst[i] = f2bf(src[i]);
}
// wxp [80][1536] -> [96][1536] zero-padded
__global__ __launch_bounds__(256) void cvt_pad_wxp(const float* __restrict__ src,
                                                   ushort* __restrict__ dst) {
    int i = blockIdx.x * 256 + threadIdx.x;
    if (i < 96 * DIN) dst[i] = (i < 80 * DIN) ? f2bf(src[i]) : (ushort)0;
}

// ---------------- LayerNorm -> bf16 out --------------------------------------
__global__ __launch_bounds__(256) void ln_kernel(const float* __restrict__ x,
                                                 const float* __restrict__ gamma,
                                                 const float* __restrict__ beta,
                                                 ushort* __restrict__ out) {
    int row = blockIdx.x;
    const float* xr = x + (size_t)row * DIMC;
    int t = threadIdx.x;
    float v0 = xr[t], v1 = xr[t + 256], v2 = xr[t + 512];
    float s = v0 + v1 + v2;
    float q = v0 * v0 + v1 * v1 + v2 * v2;
#pragma unroll
    for (int off = 32; off; off >>= 1) {
        s += __shfl_down(s, off);
        q += __shfl_down(q, off);
    }
    __shared__ float ls[4], lq[4];
    int wave = t >> 6, lane = t & 63;
    if (lane == 0) { ls[wave] = s; lq[wave] = q; }
    __syncthreads();
    float S = ls[0] + ls[1] + ls[2] + ls[3];
    float Q = lq[0] + lq[1] + lq[2] + lq[3];
    float mu = S * (1.f / DIMC);
    float var = Q * (1.f / DIMC) - mu * mu;
    float r = rsqrtf(var + 1e-5f);
    ushort* orow = out + (size_t)row * DIMC;
    orow[t]       = f2bf((v0 - mu) * r * gamma[t]       + beta[t]);
    orow[t + 256] = f2bf((v1 - mu) * r * gamma[t + 256] + beta[t + 256]);
    orow[t + 512] = f2bf((v2 - mu) * r * gamma[t + 512] + beta[t + 512]);
}

// ---------------- bf16 MFMA NT GEMM ------------------------------------------
// C[M,N] = A[M,K] . W[N,K]^T, bf16 inputs, fp32 accum.
// Tiles BM x BN, BK=32, 256 thr = 4 waves in 2x2, wave tile (BM/2)x(BN/2).
// EPI 0: store bf16 to C[M][N]
// EPI 1: store f32 C = acc + res[M][N]
// EPI 2: store f32 partial to C + blockIdx.z*(NROWS*80), cols < N (=80) only
template <int BM, int BN, int EPI>
__global__ __launch_bounds__(256) void gemm_mfma(const ushort* __restrict__ A,
                                                 const ushort* __restrict__ W,
                                                 const float* __restrict__ res,
                                                 void* __restrict__ Cout,
                                                 int K, int N, int kLen) {
    __shared__ ushort As[BM][32];
    __shared__ ushort Bs[BN][32];
    constexpr int FM = BM / 32, FN = BN / 32;
    int t = threadIdx.x;
    int bm = blockIdx.y * BM, bn = blockIdx.x * BN;
    int kBase = blockIdx.z * kLen;
    int wid = t >> 6, lane = t & 63;
    int wr = wid >> 1, wc = wid & 1;
    int lr = lane & 15, lq = lane >> 4;

    f32x4 acc[FM][FN];
#pragma unroll
    for (int m = 0; m < FM; ++m)
#pragma unroll
        for (int n = 0; n < FN; ++n) acc[m][n] = (f32x4){0.f, 0.f, 0.f, 0.f};

    for (int k0 = kBase; k0 < kBase + kLen; k0 += 32) {
#pragma unroll
        for (int u = t; u < BM * 4; u += 256) {
            int row = u >> 2, cb = u & 3;
            short8 v = *(const short8*)(A + (size_t)(bm + row) * K + k0 + cb * 8);
            *(short8*)(&As[row][cb * 8]) = v;
        }
#pragma unroll
        for (int u = t; u < BN * 4; u += 256) {
            int row = u >> 2, cb = u & 3;
            short8 v = *(const short8*)(W + (size_t)(bn + row) * K + k0 + cb * 8);
            *(short8*)(&Bs[row][cb * 8]) = v;
        }
        __syncthreads();
        short8 af[FM], bfr[FN];
#pragma unroll
        for (int m = 0; m < FM; ++m)
            af[m] = *(const short8*)(&As[wr * (BM / 2) + m * 16 + lr][lq * 8]);
#pragma unroll
        for (int n = 0; n < FN; ++n)
            bfr[n] = *(const short8*)(&Bs[wc * (BN / 2) + n * 16 + lr][lq * 8]);
#pragma unroll
        for (int m = 0; m < FM; ++m)
#pragma unroll
            for (int n = 0; n < FN; ++n)
                acc[m][n] = __builtin_amdgcn_mfma_f32_16x16x32_bf16(af[m], bfr[n], acc[m][n], 0, 0, 0);
        __syncthreads();
    }
#pragma unroll
    for (int m = 0; m < FM; ++m)
#pragma unroll
        for (int n = 0; n < FN; ++n) {
            int col = bn + wc * (BN / 2) + n * 16 + lr;
            int rbase = bm + wr * (BM / 2) + m * 16 + lq * 4;
#pragma unroll
            for (int j = 0; j < 4; ++j) {
                int row = rbase + j;
                float v = acc[m][n][j];
                if (EPI == 0) {
                    ((ushort*)Cout)[(size_t)row * N + col] = f2bf(v);
                } else if (EPI == 1) {
                    ((float*)Cout)[(size_t)row * N + col] = v + res[(size_t)row * N + col];
                } else {
                    if (col < N)
                        ((float*)Cout)[(size_t)blockIdx.z * ((size_t)NROWS * 80) + (size_t)row * 80 + col] = v;
                }
            }
        }
}

// ---------------- x_proj K-split reduce --------------------------------------
__global__ __launch_bounds__(256) void xproj_reduce(const float* __restrict__ part,
                                                    float* __restrict__ xdbl) {
    int i = blockIdx.x * 256 + threadIdx.x;  // 0 .. 4096*80-1
    float s = 0.f;
#pragma unroll
    for (int z = 0; z < 8; ++z) s += part[(size_t)z * ((size_t)NROWS * 80) + i];
    xdbl[i] = s;
}

// ---------------- fp32 NT GEMM (dt_proj only) --------------------------------
template <int EPI>
__global__ __launch_bounds__(256) void gemm_nt(const float* __restrict__ A, int lda,
                                               const float* __restrict__ W,
                                               const float* __restrict__ epi,
                                               float* __restrict__ C, int N, int K) {
    __shared__ float Asm[16][68];
    __shared__ float Bsm[16][68];
    int bm = blockIdx.y * 64, bn = blockIdx.x * 64;
    int t = threadIdx.x;
    int lr = t >> 4, lc = t & 15;
    int am = t >> 2, ak = (t & 3) * 4;
    float acc[4][4];
#pragma unroll
    for (int i = 0; i < 4; i++)
#pragma unroll
        for (int j = 0; j < 4; j++) acc[i][j] = 0.f;

    for (int k0 = 0; k0 < K; k0 += 16) {
        float4 av = *reinterpret_cast<const float4*>(A + (size_t)(bm + am) * lda + k0 + ak);
        int wrow = bn + am;
        float4 wv = make_float4(0.f, 0.f, 0.f, 0.f);
        if (wrow < N) wv = *reinterpret_cast<const float4*>(W + (size_t)wrow * K + k0 + ak);
        Asm[ak + 0][am] = av.x; Asm[ak + 1][am] = av.y;
        Asm[ak + 2][am] = av.z; Asm[ak + 3][am] = av.w;
        Bsm[ak + 0][am] = wv.x; Bsm[ak + 1][am] = wv.y;
        Bsm[ak + 2][am] = wv.z; Bsm[ak + 3][am] = wv.w;
        __syncthreads();
#pragma unroll
        for (int k = 0; k < 16; ++k) {
            float a0 = Asm[k][lr * 4 + 0], a1 = Asm[k][lr * 4 + 1];
            float a2 = Asm[k][lr * 4 + 2], a3 = Asm[k][lr * 4 + 3];
            float b0 = Bsm[k][lc * 4 + 0], b1 = Bsm[k][lc * 4 + 1];
            float b2 = Bsm[k][lc * 4 + 2], b3 = Bsm[k][lc * 4 + 3];
            acc[0][0] += a0 * b0; acc[0][1] += a0 * b1; acc[0][2] += a0 * b2; acc[0][3] += a0 * b3;
            acc[1][0] += a1 * b0; acc[1][1] += a1 * b1; acc[1][2] += a1 * b2; acc[1][3] += a1 * b3;
            acc[2][0] += a2 * b0; acc[2][1] += a2 * b1; acc[2][2] += a2 * b2; acc[2][3] += a2 * b3;
            acc[3][0] += a3 * b0; acc[3][1] += a3 * b1; acc[3][2] += a3 * b2; acc[3][3] += a3 * b3;
        }
        __syncthreads();
    }
#pragma unroll
    for (int i = 0; i < 4; ++i) {
        int row = bm + lr * 4 + i;
        float* crow = C + (size_t)row * N;
#pragma unroll
        for (int j = 0; j < 4; ++j) {
            int col = bn + lc * 4 + j;
            if (col < N) {
                float v = acc[i][j];
                if (EPI == 1) {
                    v += epi[col];
                    v = (v > 20.f) ? v : log1pf(__expf(v));
                }
                crow[col] = v;
            }
        }
    }
}

// ---------------- depthwise causal conv (bf16 in/out) ------------------------
__global__ __launch_bounds__(256) void conv_silu(const ushort* __restrict__ xz,
                                                 const float* __restrict__ cw,
                                                 const float* __restrict__ cb,
                                                 ushort* __restrict__ u) {
    int d = blockIdx.x * 256 + threadIdx.x;  // 0..1535
    int row = blockIdx.y;                    // 0..4095
    int l = row & (LSEQ - 1);
    const ushort* base = xz + (size_t)row * (2 * DIN) + d;
    float w0 = cw[d * 4 + 0], w1 = cw[d * 4 + 1], w2 = cw[d * 4 + 2], w3 = cw[d * 4 + 3];
    float acc = cb[d];
    if (l >= 3) acc += bf2f(base[-3 * 2 * DIN]) * w0;
    if (l >= 2) acc += bf2f(base[-2 * 2 * DIN]) * w1;
    if (l >= 1) acc += bf2f(base[-1 * 2 * DIN]) * w2;
    acc += bf2f(base[0]) * w3;
    u[(size_t)row * DIN + d] = f2bf(acc * sigmoidf_(acc));
}

// ---------------- chunked selective scan ------------------------------------
__global__ __launch_bounds__(256) void scan_partA(const ushort* __restrict__ u,
                                                  const float* __restrict__ delta,
                                                  const float* __restrict__ xdbl,
                                                  const float* __restrict__ A_log,
                                                  float* __restrict__ hend,
                                                  float* __restrict__ Pst) {
    int c = blockIdx.x;
    int bg = blockIdx.y;
    int b = bg / NGRP;
    int d0 = (bg % NGRP) * 16;
    int t = threadIdx.x;
    int grp = t >> 4, s = t & 15;
    int d = d0 + grp;
    float Acoef = -__expf(A_log[d * DST + s]);
    int l0 = c * CHUNK;
    const ushort* ub = u + ((size_t)b * LSEQ + l0) * DIN + d;
    const float* db = delta + ((size_t)b * LSEQ + l0) * DIN + d;
    const float* xd = xdbl + ((size_t)b * LSEQ + l0) * 80;
    float h = 0.f, P = 1.f;
    for (int l = 0; l < CHUNK; ++l) {
        float dt = db[(size_t)l * DIN];
        float uu = bf2f(ub[(size_t)l * DIN]);
        float Bv = xd[l * 80 + DTR + s];
        float dA = __expf(dt * Acoef);
        h = h * dA + dt * uu * Bv;
        P *= dA;
    }
    size_t idx = ((size_t)c * B_SZ + b) * (DIN * DST) + (size_t)d * DST + s;
    hend[idx] = h;
    Pst[idx] = P;
}

__global__ __launch_bounds__(256) void scan_partB(const float* __restrict__ hend,
                                                  const float* __restrict__ Pst,
                                                  float* __restrict__ Hinit) {
    int tid = blockIdx.x * 256 + threadIdx.x;  // 0..49151
    float H = 0.f;
#pragma unroll
    for (int c = 0; c < NCHUNK; ++c) {
        size_t idx = (size_t)c * (B_SZ * DIN * DST) + tid;
        Hinit[idx] = H;
        H = Pst[idx] * H + hend[idx];
    }
}

__global__ __launch_bounds__(256) void scan_partC(const ushort* __restrict__ u,
                                                  const float* __restrict__ delta,
                                                  const float* __restrict__ xdbl,
                                                  const ushort* __restrict__ xz,
                                                  const float* __restrict__ A_log,
                                                  const float* __restrict__ Dskip,
                                                  const float* __restrict__ Hinit,
                                                  ushort* __restrict__ yg) {
    int c = blockIdx.x;
    int bg = blockIdx.y;
    int b = bg / NGRP;
    int d0 = (bg % NGRP) * 16;
    int t = threadIdx.x;
    int grp = t >> 4, s = t & 15;
    int d = d0 + grp;
    float Acoef = -__expf(A_log[d * DST + s]);
    float Dv = Dskip[d];
    int l0 = c * CHUNK;
    const ushort* ub = u + ((size_t)b * LSEQ + l0) * DIN + d;
    const float* db = delta + ((size_t)b * LSEQ + l0) * DIN + d;
    const float* xd = xdbl + ((size_t)b * LSEQ + l0) * 80;
    const ushort* zb = xz + ((size_t)b * LSEQ + l0) * (2 * DIN) + DIN + d;
    ushort* yb = yg + ((size_t)b * LSEQ + l0) * DIN + d;
    float h = Hinit[((size_t)c * B_SZ + b) * (DIN * DST) + (size_t)d * DST + s];
    for (int l = 0; l < CHUNK; ++l) {
        float dt = db[(size_t)l * DIN];
        float uu = bf2f(ub[(size_t)l * DIN]);
        float Bv = xd[l * 80 + DTR + s];
        float Cv = xd[l * 80 + DTR + DST + s];
        float dA = __expf(dt * Acoef);
        h = h * dA + dt * uu * Bv;
        float cc = h * Cv;
        cc += __shfl_xor(cc, 1);
        cc += __shfl_xor(cc, 2);
        cc += __shfl_xor(cc, 4);
        cc += __shfl_xor(cc, 8);
        if (s == 0) {
            float z = bf2f(zb[(size_t)l * (2 * DIN)]);
            float y = cc + uu * Dv;
            yb[(size_t)l * DIN] = f2bf(y * (z * sigmoidf_(z)));
        }
    }
}

extern "C" void kernel_launch(void* const* d_in, const int* in_sizes, int n_in,
                              void* d_out, int out_size, void* d_ws, size_t ws_size,
                              hipStream_t stream) {
    const float* x    = (const float*)d_in[0];
    const float* lng  = (const float*)d_in[1];
    const float* lnb  = (const float*)d_in[2];
    const float* win  = (const float*)d_in[3];
    const float* cw   = (const float*)d_in[4];
    const float* cb   = (const float*)d_in[5];
    const float* wxp  = (const float*)d_in[6];
    const float* wdt  = (const float*)d_in[7];
    const float* bdt  = (const float*)d_in[8];
    const float* alog = (const float*)d_in[9];
    const float* dsk  = (const float*)d_in[10];
    const float* wout = (const float*)d_in[11];
    float* out = (float*)d_out;

    char* wsb = (char*)d_ws;
    size_t off = 0;
    auto alloc = [&](size_t bytes) { char* p = wsb + off; off += (bytes + 255) & ~255ull; return p; };
    ushort* xz_b   = (ushort*)alloc((size_t)NROWS * 2 * DIN * 2);  // 25.2 MB
    ushort* u_b    = (ushort*)alloc((size_t)NROWS * DIN * 2);      // 12.6 MB
    float*  delta  = (float*) alloc((size_t)NROWS * DIN * 4);      // 25.2 MB (early: xpart 10.5 MB)
    float*  xdbl   = (float*) alloc((size_t)NROWS * 80 * 4);       // 1.3 MB
    ushort* yg_b   = (ushort*)alloc((size_t)NROWS * DIN * 2);      // 12.6 MB
    char*   R      = alloc(11010048);                              // hln+win  / hend+Pst+Hinit
    ushort* wout_b = (ushort*)alloc((size_t)DIMC * DIN * 2);       // 2.36 MB
    ushort* wxp_b  = (ushort*)alloc((size_t)96 * DIN * 2);         // 0.29 MB
    ushort* hln_b  = (ushort*)R;                 // 6.29 MB, dead after in_proj
    ushort* win_b  = (ushort*)(R + 6291456);     // 4.72 MB, dead after in_proj
    float*  hend   = (float*)R;                  // 3.15 MB
    float*  Pst    = (float*)(R + 3145728);      // 3.15 MB
    float*  Hinit  = (float*)(R + 6291456);      // 3.15 MB
    float*  xpart  = delta;                      // 8 * 4096*80 * 4 = 10.5 MB

    cvt_bf16<<<9216, 256, 0, stream>>>(win, win_b, 2 * DIN * DIMC);
    cvt_bf16<<<4608, 256, 0, stream>>>(wout, wout_b, DIMC * DIN);
    cvt_pad_wxp<<<576, 256, 0, stream>>>(wxp, wxp_b);
    ln_kernel<<<NROWS, 256, 0, stream>>>(x, lng, lnb, hln_b);
    gemm_mfma<128, 128, 0><<<dim3(24, 32, 1), 256, 0, stream>>>(hln_b, win_b, nullptr, xz_b, DIMC, 2 * DIN, DIMC);
    conv_silu<<<dim3(6, NROWS), 256, 0, stream>>>(xz_b, cw, cb, u_b);
    gemm_mfma<128, 96, 2><<<dim3(1, 32, 8), 256, 0, stream>>>(u_b, wxp_b, nullptr, xpart, DIN, 80, DIN / 8);
    xproj_reduce<<<1280, 256, 0, stream>>>(xpart, xdbl);
    gemm_nt<1><<<dim3(24, 64), 256, 0, stream>>>(xdbl, 80, wdt, bdt, delta, DIN, DTR);
    scan_partA<<<dim3(NCHUNK, B_SZ * NGRP), 256, 0, stream>>>(u_b, delta, xdbl, alog, hend, Pst);
    scan_partB<<<B_SZ * DIN * DST / 256, 256, 0, stream>>>(hend, Pst, Hinit);
    scan_partC<<<dim3(NCHUNK, B_SZ * NGRP), 256, 0, stream>>>(u_b, delta, xdbl, xz_b, alog, dsk, Hinit, yg_b);
    gemm_mfma<128, 64, 1><<<dim3(12, 32, 1), 256, 0, stream>>>(yg_b, wout_b, x, out, DIN, DIMC, DIN);
}

// Round 4
// 354.336 us; speedup vs baseline: 6.4152x; 1.3650x over previous
//
#include <hip/hip_runtime.h>
#include <math.h>

#define B_SZ 2
#define LSEQ 2048
#define DIMC 768
#define DIN 1536
#define DTR 48
#define DST 16
#define NROWS (B_SZ * LSEQ)
#define CHUNK 32
#define NCHUNK (LSEQ / CHUNK)   // 64
#define LOG2E 1.4426950408889634f

typedef __attribute__((ext_vector_type(8))) short short8;
typedef __attribute__((ext_vector_type(4))) float f32x4;
typedef unsigned short ushort;

__device__ __forceinline__ float sigmoidf_(float x) { return 1.f / (1.f + __expf(-x)); }

__device__ __forceinline__ ushort f2bf(float f) {
    union { float f; unsigned u; } v; v.f = f;
    unsigned r = v.u + 0x7FFFu + ((v.u >> 16) & 1u);
    return (ushort)(r >> 16);
}
__device__ __forceinline__ float bf2f(ushort h) {
    union { unsigned u; float f; } v; v.u = ((unsigned)h) << 16; return v.f;
}

// ---------------- weight fp32 -> bf16 conversion ----------------------------
__global__ __launch_bounds__(256) void cvt_bf16(const float* __restrict__ src,
                                                ushort* __restrict__ dst, int n) {
    int i = blockIdx.x * 256 + threadIdx.x;
    if (i < n) dst[i] = f2bf(src[i]);
}
__global__ __launch_bounds__(256) void cvt_pad_wxp(const float* __restrict__ src,
                                                   ushort* __restrict__ dst) {
    int i = blockIdx.x * 256 + threadIdx.x;
    if (i < 96 * DIN) dst[i] = (i < 80 * DIN) ? f2bf(src[i]) : (ushort)0;
}

// ---------------- LayerNorm -> bf16 out --------------------------------------
__global__ __launch_bounds__(256) void ln_kernel(const float* __restrict__ x,
                                                 const float* __restrict__ gamma,
                                                 const float* __restrict__ beta,
                                                 ushort* __restrict__ out) {
    int row = blockIdx.x;
    const float* xr = x + (size_t)row * DIMC;
    int t = threadIdx.x;
    float v0 = xr[t], v1 = xr[t + 256], v2 = xr[t + 512];
    float s = v0 + v1 + v2;
    float q = v0 * v0 + v1 * v1 + v2 * v2;
#pragma unroll
    for (int off = 32; off; off >>= 1) {
        s += __shfl_down(s, off);
        q += __shfl_down(q, off);
    }
    __shared__ float ls[4], lq[4];
    int wave = t >> 6, lane = t & 63;
    if (lane == 0) { ls[wave] = s; lq[wave] = q; }
    __syncthreads();
    float S = ls[0] + ls[1] + ls[2] + ls[3];
    float Q = lq[0] + lq[1] + lq[2] + lq[3];
    float mu = S * (1.f / DIMC);
    float var = Q * (1.f / DIMC) - mu * mu;
    float r = rsqrtf(var + 1e-5f);
    ushort* orow = out + (size_t)row * DIMC;
    orow[t]       = f2bf((v0 - mu) * r * gamma[t]       + beta[t]);
    orow[t + 256] = f2bf((v1 - mu) * r * gamma[t + 256] + beta[t + 256]);
    orow[t + 512] = f2bf((v2 - mu) * r * gamma[t + 512] + beta[t + 512]);
}

// ---------------- bf16 MFMA NT GEMM ------------------------------------------
template <int BM, int BN, int EPI>
__global__ __launch_bounds__(256) void gemm_mfma(const ushort* __restrict__ A,
                                                 const ushort* __restrict__ W,
                                                 const float* __restrict__ res,
                                                 void* __restrict__ Cout,
                                                 int K, int N, int kLen) {
    __shared__ ushort As[BM][32];
    __shared__ ushort Bs[BN][32];
    constexpr int FM = BM / 32, FN = BN / 32;
    int t = threadIdx.x;
    int bm = blockIdx.y * BM, bn = blockIdx.x * BN;
    int kBase = blockIdx.z * kLen;
    int wid = t >> 6, lane = t & 63;
    int wr = wid >> 1, wc = wid & 1;
    int lr = lane & 15, lq = lane >> 4;

    f32x4 acc[FM][FN];
#pragma unroll
    for (int m = 0; m < FM; ++m)
#pragma unroll
        for (int n = 0; n < FN; ++n) acc[m][n] = (f32x4){0.f, 0.f, 0.f, 0.f};

    for (int k0 = kBase; k0 < kBase + kLen; k0 += 32) {
#pragma unroll
        for (int u = t; u < BM * 4; u += 256) {
            int row = u >> 2, cb = u & 3;
            short8 v = *(const short8*)(A + (size_t)(bm + row) * K + k0 + cb * 8);
            *(short8*)(&As[row][cb * 8]) = v;
        }
#pragma unroll
        for (int u = t; u < BN * 4; u += 256) {
            int row = u >> 2, cb = u & 3;
            short8 v = *(const short8*)(W + (size_t)(bn + row) * K + k0 + cb * 8);
            *(short8*)(&Bs[row][cb * 8]) = v;
        }
        __syncthreads();
        short8 af[FM], bfr[FN];
#pragma unroll
        for (int m = 0; m < FM; ++m)
            af[m] = *(const short8*)(&As[wr * (BM / 2) + m * 16 + lr][lq * 8]);
#pragma unroll
        for (int n = 0; n < FN; ++n)
            bfr[n] = *(const short8*)(&Bs[wc * (BN / 2) + n * 16 + lr][lq * 8]);
#pragma unroll
        for (int m = 0; m < FM; ++m)
#pragma unroll
            for (int n = 0; n < FN; ++n)
                acc[m][n] = __builtin_amdgcn_mfma_f32_16x16x32_bf16(af[m], bfr[n], acc[m][n], 0, 0, 0);
        __syncthreads();
    }
#pragma unroll
    for (int m = 0; m < FM; ++m)
#pragma unroll
        for (int n = 0; n < FN; ++n) {
            int col = bn + wc * (BN / 2) + n * 16 + lr;
            int rbase = bm + wr * (BM / 2) + m * 16 + lq * 4;
#pragma unroll
            for (int j = 0; j < 4; ++j) {
                int row = rbase + j;
                float v = acc[m][n][j];
                if (EPI == 0) {
                    ((ushort*)Cout)[(size_t)row * N + col] = f2bf(v);
                } else if (EPI == 1) {
                    ((float*)Cout)[(size_t)row * N + col] = v + res[(size_t)row * N + col];
                } else {
                    if (col < N)
                        ((float*)Cout)[(size_t)blockIdx.z * ((size_t)NROWS * 80) + (size_t)row * 80 + col] = v;
                }
            }
        }
}

// ---------------- x_proj K-split reduce --------------------------------------
__global__ __launch_bounds__(256) void xproj_reduce(const float* __restrict__ part,
                                                    float* __restrict__ xdbl) {
    int i = blockIdx.x * 256 + threadIdx.x;  // 0 .. 4096*80-1
    float s = 0.f;
#pragma unroll
    for (int z = 0; z < 8; ++z) s += part[(size_t)z * ((size_t)NROWS * 80) + i];
    xdbl[i] = s;
}

// ---------------- fp32 NT GEMM (dt_proj only) --------------------------------
template <int EPI>
__global__ __launch_bounds__(256) void gemm_nt(const float* __restrict__ A, int lda,
                                               const float* __restrict__ W,
                                               const float* __restrict__ epi,
                                               float* __restrict__ C, int N, int K) {
    __shared__ float Asm[16][68];
    __shared__ float Bsm[16][68];
    int bm = blockIdx.y * 64, bn = blockIdx.x * 64;
    int t = threadIdx.x;
    int lr = t >> 4, lc = t & 15;
    int am = t >> 2, ak = (t & 3) * 4;
    float acc[4][4];
#pragma unroll
    for (int i = 0; i < 4; i++)
#pragma unroll
        for (int j = 0; j < 4; j++) acc[i][j] = 0.f;

    for (int k0 = 0; k0 < K; k0 += 16) {
        float4 av = *reinterpret_cast<const float4*>(A + (size_t)(bm + am) * lda + k0 + ak);
        int wrow = bn + am;
        float4 wv = make_float4(0.f, 0.f, 0.f, 0.f);
        if (wrow < N) wv = *reinterpret_cast<const float4*>(W + (size_t)wrow * K + k0 + ak);
        Asm[ak + 0][am] = av.x; Asm[ak + 1][am] = av.y;
        Asm[ak + 2][am] = av.z; Asm[ak + 3][am] = av.w;
        Bsm[ak + 0][am] = wv.x; Bsm[ak + 1][am] = wv.y;
        Bsm[ak + 2][am] = wv.z; Bsm[ak + 3][am] = wv.w;
        __syncthreads();
#pragma unroll
        for (int k = 0; k < 16; ++k) {
            float a0 = Asm[k][lr * 4 + 0], a1 = Asm[k][lr * 4 + 1];
            float a2 = Asm[k][lr * 4 + 2], a3 = Asm[k][lr * 4 + 3];
            float b0 = Bsm[k][lc * 4 + 0], b1 = Bsm[k][lc * 4 + 1];
            float b2 = Bsm[k][lc * 4 + 2], b3 = Bsm[k][lc * 4 + 3];
            acc[0][0] += a0 * b0; acc[0][1] += a0 * b1; acc[0][2] += a0 * b2; acc[0][3] += a0 * b3;
            acc[1][0] += a1 * b0; acc[1][1] += a1 * b1; acc[1][2] += a1 * b2; acc[1][3] += a1 * b3;
            acc[2][0] += a2 * b0; acc[2][1] += a2 * b1; acc[2][2] += a2 * b2; acc[2][3] += a2 * b3;
            acc[3][0] += a3 * b0; acc[3][1] += a3 * b1; acc[3][2] += a3 * b2; acc[3][3] += a3 * b3;
        }
        __syncthreads();
    }
#pragma unroll
    for (int i = 0; i < 4; ++i) {
        int row = bm + lr * 4 + i;
        float* crow = C + (size_t)row * N;
#pragma unroll
        for (int j = 0; j < 4; ++j) {
            int col = bn + lc * 4 + j;
            if (col < N) {
                float v = acc[i][j];
                if (EPI == 1) {
                    v += epi[col];
                    v = (v > 20.f) ? v : log1pf(__expf(v));
                }
                crow[col] = v;
            }
        }
    }
}

// ---------------- depthwise causal conv (bf16 in/out) ------------------------
__global__ __launch_bounds__(256) void conv_silu(const ushort* __restrict__ xz,
                                                 const float* __restrict__ cw,
                                                 const float* __restrict__ cb,
                                                 ushort* __restrict__ u) {
    int d = blockIdx.x * 256 + threadIdx.x;  // 0..1535
    int row = blockIdx.y;                    // 0..4095
    int l = row & (LSEQ - 1);
    const ushort* base = xz + (size_t)row * (2 * DIN) + d;
    float w0 = cw[d * 4 + 0], w1 = cw[d * 4 + 1], w2 = cw[d * 4 + 2], w3 = cw[d * 4 + 3];
    float acc = cb[d];
    if (l >= 3) acc += bf2f(base[-3 * 2 * DIN]) * w0;
    if (l >= 2) acc += bf2f(base[-2 * 2 * DIN]) * w1;
    if (l >= 1) acc += bf2f(base[-1 * 2 * DIN]) * w2;
    acc += bf2f(base[0]) * w3;
    u[(size_t)row * DIN + d] = f2bf(acc * sigmoidf_(acc));
}

// ---------------- chunked selective scan: lane = (chunk,b,d), states in regs --
// hend/Hinit layout [c][b][d][s]; sumdt layout [c][b][d]
__global__ __launch_bounds__(256) void scan_partA(const ushort* __restrict__ u,
                                                  const float* __restrict__ delta,
                                                  const float* __restrict__ xdbl,
                                                  const float* __restrict__ A_log,
                                                  float* __restrict__ hend,
                                                  float* __restrict__ sumdt) {
    int d = blockIdx.x * 256 + threadIdx.x;  // 0..1535
    int c = blockIdx.y;                      // 0..NCHUNK-1
    int b = blockIdx.z;                      // 0..1
    float Ac2[16];
    const float4* Arow = (const float4*)(A_log + (size_t)d * DST);
#pragma unroll
    for (int q = 0; q < 4; ++q) {
        float4 a = Arow[q];
        Ac2[q * 4 + 0] = -__expf(a.x) * LOG2E;
        Ac2[q * 4 + 1] = -__expf(a.y) * LOG2E;
        Ac2[q * 4 + 2] = -__expf(a.z) * LOG2E;
        Ac2[q * 4 + 3] = -__expf(a.w) * LOG2E;
    }
    int l0 = c * CHUNK;
    const float* db = delta + ((size_t)b * LSEQ + l0) * DIN + d;
    const ushort* ub = u + ((size_t)b * LSEQ + l0) * DIN + d;
    const float* xB0 = xdbl + ((size_t)b * LSEQ + l0) * 80 + DTR;
    float h[16];
#pragma unroll
    for (int s = 0; s < 16; ++s) h[s] = 0.f;
    float sdt = 0.f;
#pragma unroll 2
    for (int l = 0; l < CHUNK; ++l) {
        float dt = db[(size_t)l * DIN];
        float uu = bf2f(ub[(size_t)l * DIN]);
        sdt += dt;
        float dtu = dt * uu;
        const float4* xB = (const float4*)(xB0 + l * 80);
        float4 b0 = xB[0], b1 = xB[1], b2 = xB[2], b3 = xB[3];
        float bv[16] = {b0.x, b0.y, b0.z, b0.w, b1.x, b1.y, b1.z, b1.w,
                        b2.x, b2.y, b2.z, b2.w, b3.x, b3.y, b3.z, b3.w};
#pragma unroll
        for (int s = 0; s < 16; ++s)
            h[s] = h[s] * exp2f(dt * Ac2[s]) + dtu * bv[s];
    }
    size_t obase = (((size_t)c * B_SZ + b) * DIN + d) * DST;
    float4* ho = (float4*)(hend + obase);
#pragma unroll
    for (int q = 0; q < 4; ++q)
        ho[q] = make_float4(h[q * 4 + 0], h[q * 4 + 1], h[q * 4 + 2], h[q * 4 + 3]);
    sumdt[((size_t)c * B_SZ + b) * DIN + d] = sdt;
}

// Pass B: thread = (b*DIN+d)*16+s; serial combine over chunks, P from sumdt.
__global__ __launch_bounds__(256) void scan_partB(const float* __restrict__ hend,
                                                  const float* __restrict__ sumdt,
                                                  const float* __restrict__ A_log,
                                                  float* __restrict__ Hinit) {
    int tid = blockIdx.x * 256 + threadIdx.x;  // 0..49151
    int s = tid & 15;
    int bd = tid >> 4;       // b*DIN+d
    int d = bd % DIN;
    float Ac2 = -__expf(A_log[(size_t)d * DST + s]) * LOG2E;
    float H = 0.f;
    for (int c = 0; c < NCHUNK; ++c) {
        size_t idx = (size_t)c * (B_SZ * DIN * DST) + tid;
        Hinit[idx] = H;
        float P = exp2f(sumdt[(size_t)c * (B_SZ * DIN) + bd] * Ac2);
        H = P * H + hend[idx];
    }
}

__global__ __launch_bounds__(256) void scan_partC(const ushort* __restrict__ u,
                                                  const float* __restrict__ delta,
                                                  const float* __restrict__ xdbl,
                                                  const ushort* __restrict__ xz,
                                                  const float* __restrict__ A_log,
                                                  const float* __restrict__ Dskip,
                                                  const float* __restrict__ Hinit,
                                                  ushort* __restrict__ yg) {
    int d = blockIdx.x * 256 + threadIdx.x;
    int c = blockIdx.y;
    int b = blockIdx.z;
    float Ac2[16];
    const float4* Arow = (const float4*)(A_log + (size_t)d * DST);
#pragma unroll
    for (int q = 0; q < 4; ++q) {
        float4 a = Arow[q];
        Ac2[q * 4 + 0] = -__expf(a.x) * LOG2E;
        Ac2[q * 4 + 1] = -__expf(a.y) * LOG2E;
        Ac2[q * 4 + 2] = -__expf(a.z) * LOG2E;
        Ac2[q * 4 + 3] = -__expf(a.w) * LOG2E;
    }
    float Dv = Dskip[d];
    int l0 = c * CHUNK;
    const float* db = delta + ((size_t)b * LSEQ + l0) * DIN + d;
    const ushort* ub = u + ((size_t)b * LSEQ + l0) * DIN + d;
    const float* xB0 = xdbl + ((size_t)b * LSEQ + l0) * 80 + DTR;
    const ushort* zb = xz + ((size_t)b * LSEQ + l0) * (2 * DIN) + DIN + d;
    ushort* yb = yg + ((size_t)b * LSEQ + l0) * DIN + d;
    float h[16];
    const float4* hi = (const float4*)(Hinit + (((size_t)c * B_SZ + b) * DIN + d) * DST);
#pragma unroll
    for (int q = 0; q < 4; ++q) {
        float4 v = hi[q];
        h[q * 4 + 0] = v.x; h[q * 4 + 1] = v.y; h[q * 4 + 2] = v.z; h[q * 4 + 3] = v.w;
    }
#pragma unroll 2
    for (int l = 0; l < CHUNK; ++l) {
        float dt = db[(size_t)l * DIN];
        float uu = bf2f(ub[(size_t)l * DIN]);
        float dtu = dt * uu;
        const float4* xB = (const float4*)(xB0 + l * 80);
        float4 b0 = xB[0], b1 = xB[1], b2 = xB[2], b3 = xB[3];
        float4 c0 = xB[4], c1 = xB[5], c2 = xB[6], c3 = xB[7];
        float bv[16] = {b0.x, b0.y, b0.z, b0.w, b1.x, b1.y, b1.z, b1.w,
                        b2.x, b2.y, b2.z, b2.w, b3.x, b3.y, b3.z, b3.w};
        float cv[16] = {c0.x, c0.y, c0.z, c0.w, c1.x, c1.y, c1.z, c1.w,
                        c2.x, c2.y, c2.z, c2.w, c3.x, c3.y, c3.z, c3.w};
        float acc = 0.f;
#pragma unroll
        for (int s = 0; s < 16; ++s) {
            h[s] = h[s] * exp2f(dt * Ac2[s]) + dtu * bv[s];
            acc = fmaf(h[s], cv[s], acc);
        }
        float z = bf2f(zb[(size_t)l * (2 * DIN)]);
        float y = acc + uu * Dv;
        yb[(size_t)l * DIN] = f2bf(y * (z * sigmoidf_(z)));
    }
}

extern "C" void kernel_launch(void* const* d_in, const int* in_sizes, int n_in,
                              void* d_out, int out_size, void* d_ws, size_t ws_size,
                              hipStream_t stream) {
    const float* x    = (const float*)d_in[0];
    const float* lng  = (const float*)d_in[1];
    const float* lnb  = (const float*)d_in[2];
    const float* win  = (const float*)d_in[3];
    const float* cw   = (const float*)d_in[4];
    const float* cb   = (const float*)d_in[5];
    const float* wxp  = (const float*)d_in[6];
    const float* wdt  = (const float*)d_in[7];
    const float* bdt  = (const float*)d_in[8];
    const float* alog = (const float*)d_in[9];
    const float* dsk  = (const float*)d_in[10];
    const float* wout = (const float*)d_in[11];
    float* out = (float*)d_out;

    char* wsb = (char*)d_ws;
    size_t off = 0;
    auto alloc = [&](size_t bytes) { char* p = wsb + off; off += (bytes + 255) & ~255ull; return p; };
    ushort* xz_b   = (ushort*)alloc((size_t)NROWS * 2 * DIN * 2);  // 25.2 MB
    ushort* u_b    = (ushort*)alloc((size_t)NROWS * DIN * 2);      // 12.6 MB
    float*  delta  = (float*) alloc((size_t)NROWS * DIN * 4);      // 25.2 MB (early: xpart)
    float*  xdbl   = (float*) alloc((size_t)NROWS * 80 * 4);       // 1.3 MB
    ushort* yg_b   = (ushort*)alloc((size_t)NROWS * DIN * 2);      // 12.6 MB
    char*   R      = alloc(26000000);                              // overlay region
    ushort* wout_b = (ushort*)alloc((size_t)DIMC * DIN * 2);       // 2.36 MB
    ushort* wxp_b  = (ushort*)alloc((size_t)96 * DIN * 2);         // 0.29 MB
    // overlay 1 (pre-in_proj): hln + win_b
    ushort* hln_b  = (ushort*)R;                 // 6.29 MB
    ushort* win_b  = (ushort*)(R + 6291456);     // 4.72 MB
    // overlay 2 (scan): hend + Hinit + sumdt
    float*  hend   = (float*)R;                        // 12.58 MB
    float*  Hinit  = (float*)(R + 12582912);           // 12.58 MB
    float*  sumdt  = (float*)(R + 25165824);           // 0.79 MB
    float*  xpart  = delta;                      // 8 * 4096*80*4 = 10.5 MB

    cvt_bf16<<<9216, 256, 0, stream>>>(win, win_b, 2 * DIN * DIMC);
    cvt_bf16<<<4608, 256, 0, stream>>>(wout, wout_b, DIMC * DIN);
    cvt_pad_wxp<<<576, 256, 0, stream>>>(wxp, wxp_b);
    ln_kernel<<<NROWS, 256, 0, stream>>>(x, lng, lnb, hln_b);
    gemm_mfma<128, 128, 0><<<dim3(24, 32, 1), 256, 0, stream>>>(hln_b, win_b, nullptr, xz_b, DIMC, 2 * DIN, DIMC);
    conv_silu<<<dim3(6, NROWS), 256, 0, stream>>>(xz_b, cw, cb, u_b);
    gemm_mfma<128, 96, 2><<<dim3(1, 32, 8), 256, 0, stream>>>(u_b, wxp_b, nullptr, xpart, DIN, 80, DIN / 8);
    xproj_reduce<<<1280, 256, 0, stream>>>(xpart, xdbl);
    gemm_nt<1><<<dim3(24, 64), 256, 0, stream>>>(xdbl, 80, wdt, bdt, delta, DIN, DTR);
    scan_partA<<<dim3(6, NCHUNK, B_SZ), 256, 0, stream>>>(u_b, delta, xdbl, alog, hend, sumdt);
    scan_partB<<<192, 256, 0, stream>>>(hend, sumdt, alog, Hinit);
    scan_partC<<<dim3(6, NCHUNK, B_SZ), 256, 0, stream>>>(u_b, delta, xdbl, xz_b, alog, dsk, Hinit, yg_b);
    gemm_mfma<128, 64, 1><<<dim3(12, 32, 1), 256, 0, stream>>>(yg_b, wout_b, x, out, DIN, DIMC, DIN);
}

// Round 5
// 347.932 us; speedup vs baseline: 6.5333x; 1.0184x over previous
//
#include <hip/hip_runtime.h>
#include <math.h>

#define B_SZ 2
#define LSEQ 2048
#define DIMC 768
#define DIN 1536
#define DTR 48
#define DST 16
#define NROWS (B_SZ * LSEQ)
#define CHUNK 16
#define NCHUNK (LSEQ / CHUNK)   // 128
#define LOG2E 1.4426950408889634f

typedef __attribute__((ext_vector_type(8))) short short8;
typedef __attribute__((ext_vector_type(4))) float f32x4;
typedef unsigned short ushort;

__device__ __forceinline__ float sigmoidf_(float x) { return 1.f / (1.f + __expf(-x)); }

__device__ __forceinline__ ushort f2bf(float f) {
    union { float f; unsigned u; } v; v.f = f;
    unsigned r = v.u + 0x7FFFu + ((v.u >> 16) & 1u);
    return (ushort)(r >> 16);
}
__device__ __forceinline__ float bf2f(ushort h) {
    union { unsigned u; float f; } v; v.u = ((unsigned)h) << 16; return v.f;
}

// ---------------- fused weight conversion ------------------------------------
// [0, NW1): win -> win_b
// [NW1, NW1+NW2): wout -> wout_b
// next 96*1536: wxp zero-padded 80->96 rows
// next 1536*64: wdt [1536][48] -> [1536][64] zero-padded cols
#define NW1 (2 * DIN * DIMC)
#define NW2 (DIMC * DIN)
#define NW3 (96 * DIN)
#define NW4 (DIN * 64)
__global__ __launch_bounds__(256) void cvt_all(const float* __restrict__ win,
                                               const float* __restrict__ wout,
                                               const float* __restrict__ wxp,
                                               const float* __restrict__ wdt,
                                               ushort* __restrict__ win_b,
                                               ushort* __restrict__ wout_b,
                                               ushort* __restrict__ wxp_b,
                                               ushort* __restrict__ wdt_b) {
    int i = blockIdx.x * 256 + threadIdx.x;
    if (i < NW1) {
        win_b[i] = f2bf(win[i]);
    } else if ((i -= NW1) < NW2) {
        wout_b[i] = f2bf(wout[i]);
    } else if ((i -= NW2) < NW3) {
        wxp_b[i] = (i < 80 * DIN) ? f2bf(wxp[i]) : (ushort)0;
    } else if ((i -= NW3) < NW4) {
        int r = i >> 6, c = i & 63;
        wdt_b[i] = (c < DTR) ? f2bf(wdt[r * DTR + c]) : (ushort)0;
    }
}

// ---------------- LayerNorm -> bf16 out --------------------------------------
__global__ __launch_bounds__(256) void ln_kernel(const float* __restrict__ x,
                                                 const float* __restrict__ gamma,
                                                 const float* __restrict__ beta,
                                                 ushort* __restrict__ out) {
    int row = blockIdx.x;
    const float* xr = x + (size_t)row * DIMC;
    int t = threadIdx.x;
    float v0 = xr[t], v1 = xr[t + 256], v2 = xr[t + 512];
    float s = v0 + v1 + v2;
    float q = v0 * v0 + v1 * v1 + v2 * v2;
#pragma unroll
    for (int off = 32; off; off >>= 1) {
        s += __shfl_down(s, off);
        q += __shfl_down(q, off);
    }
    __shared__ float ls[4], lq[4];
    int wave = t >> 6, lane = t & 63;
    if (lane == 0) { ls[wave] = s; lq[wave] = q; }
    __syncthreads();
    float S = ls[0] + ls[1] + ls[2] + ls[3];
    float Q = lq[0] + lq[1] + lq[2] + lq[3];
    float mu = S * (1.f / DIMC);
    float var = Q * (1.f / DIMC) - mu * mu;
    float r = rsqrtf(var + 1e-5f);
    ushort* orow = out + (size_t)row * DIMC;
    orow[t]       = f2bf((v0 - mu) * r * gamma[t]       + beta[t]);
    orow[t + 256] = f2bf((v1 - mu) * r * gamma[t + 256] + beta[t + 256]);
    orow[t + 512] = f2bf((v2 - mu) * r * gamma[t + 512] + beta[t + 512]);
}

// ---------------- bf16 MFMA NT GEMM ------------------------------------------
// C[M,N] = A[M,lda(first K cols)] . W[N,K]^T, bf16 in, fp32 accum.
// BK=32, 256 thr = 4 waves 2x2, wave tile (BM/2)x(BN/2).
// EPI 0: bf16 store; 1: f32 v+res[row*N+col]; 2: f32 partial (K-split, col<N);
// EPI 3: f32 softplus(v + res[col])
// LDS rows padded to 40 ushorts (80 B) -> conflict-free ds_read_b128.
template <int BM, int BN, int EPI>
__global__ __launch_bounds__(256) void gemm_mfma(const ushort* __restrict__ A, int lda,
                                                 const ushort* __restrict__ W,
                                                 const float* __restrict__ res,
                                                 void* __restrict__ Cout,
                                                 int K, int N, int kLen) {
    __shared__ ushort As[BM][40];
    __shared__ ushort Bs[BN][40];
    constexpr int FM = BM / 32, FN = BN / 32;
    int t = threadIdx.x;
    int bm = blockIdx.y * BM, bn = blockIdx.x * BN;
    int kBase = blockIdx.z * kLen;
    int wid = t >> 6, lane = t & 63;
    int wr = wid >> 1, wc = wid & 1;
    int lr = lane & 15, lq = lane >> 4;

    f32x4 acc[FM][FN];
#pragma unroll
    for (int m = 0; m < FM; ++m)
#pragma unroll
        for (int n = 0; n < FN; ++n) acc[m][n] = (f32x4){0.f, 0.f, 0.f, 0.f};

    for (int k0 = kBase; k0 < kBase + kLen; k0 += 32) {
#pragma unroll
        for (int u = t; u < BM * 4; u += 256) {
            int row = u >> 2, cb = u & 3;
            short8 v = *(const short8*)(A + (size_t)(bm + row) * lda + k0 + cb * 8);
            *(short8*)(&As[row][cb * 8]) = v;
        }
#pragma unroll
        for (int u = t; u < BN * 4; u += 256) {
            int row = u >> 2, cb = u & 3;
            short8 v = *(const short8*)(W + (size_t)(bn + row) * K + k0 + cb * 8);
            *(short8*)(&Bs[row][cb * 8]) = v;
        }
        __syncthreads();
        short8 af[FM], bfr[FN];
#pragma unroll
        for (int m = 0; m < FM; ++m)
            af[m] = *(const short8*)(&As[wr * (BM / 2) + m * 16 + lr][lq * 8]);
#pragma unroll
        for (int n = 0; n < FN; ++n)
            bfr[n] = *(const short8*)(&Bs[wc * (BN / 2) + n * 16 + lr][lq * 8]);
#pragma unroll
        for (int m = 0; m < FM; ++m)
#pragma unroll
            for (int n = 0; n < FN; ++n)
                acc[m][n] = __builtin_amdgcn_mfma_f32_16x16x32_bf16(af[m], bfr[n], acc[m][n], 0, 0, 0);
        __syncthreads();
    }
#pragma unroll
    for (int m = 0; m < FM; ++m)
#pragma unroll
        for (int n = 0; n < FN; ++n) {
            int col = bn + wc * (BN / 2) + n * 16 + lr;
            int rbase = bm + wr * (BM / 2) + m * 16 + lq * 4;
#pragma unroll
            for (int j = 0; j < 4; ++j) {
                int row = rbase + j;
                float v = acc[m][n][j];
                if (EPI == 0) {
                    ((ushort*)Cout)[(size_t)row * N + col] = f2bf(v);
                } else if (EPI == 1) {
                    ((float*)Cout)[(size_t)row * N + col] = v + res[(size_t)row * N + col];
                } else if (EPI == 2) {
                    if (col < N)
                        ((float*)Cout)[(size_t)blockIdx.z * ((size_t)NROWS * 80) + (size_t)row * 80 + col] = v;
                } else {
                    float w = v + res[col];
                    ((float*)Cout)[(size_t)row * N + col] = (w > 20.f) ? w : log1pf(__expf(w));
                }
            }
        }
}

// ---------------- x_proj K-split reduce + bf16 pad for dt_proj ---------------
__global__ __launch_bounds__(256) void xproj_reduce(const float* __restrict__ part,
                                                    float* __restrict__ xdbl,
                                                    ushort* __restrict__ xpad_b) {
    int i = blockIdx.x * 256 + threadIdx.x;  // 0 .. 4096*80-1
    float s = 0.f;
#pragma unroll
    for (int z = 0; z < 8; ++z) s += part[(size_t)z * ((size_t)NROWS * 80) + i];
    xdbl[i] = s;
    int row = i / 80, col = i - row * 80;
    if (col < DTR) xpad_b[(size_t)row * 64 + col] = f2bf(s);
}

// ---------------- depthwise causal conv (bf16 in/out) ------------------------
__global__ __launch_bounds__(256) void conv_silu(const ushort* __restrict__ xz,
                                                 const float* __restrict__ cw,
                                                 const float* __restrict__ cb,
                                                 ushort* __restrict__ u) {
    int d = blockIdx.x * 256 + threadIdx.x;  // 0..1535
    int row = blockIdx.y;                    // 0..4095
    int l = row & (LSEQ - 1);
    const ushort* base = xz + (size_t)row * (2 * DIN) + d;
    float w0 = cw[d * 4 + 0], w1 = cw[d * 4 + 1], w2 = cw[d * 4 + 2], w3 = cw[d * 4 + 3];
    float acc = cb[d];
    if (l >= 3) acc += bf2f(base[-3 * 2 * DIN]) * w0;
    if (l >= 2) acc += bf2f(base[-2 * 2 * DIN]) * w1;
    if (l >= 1) acc += bf2f(base[-1 * 2 * DIN]) * w2;
    acc += bf2f(base[0]) * w3;
    u[(size_t)row * DIN + d] = f2bf(acc * sigmoidf_(acc));
}

// ---------------- chunked selective scan: lane = (chunk,b,d), states in regs --
// hend/Hinit layout [c][b][d][s]; sumdt layout [c][b][d]
__global__ __launch_bounds__(256) void scan_partA(const ushort* __restrict__ u,
                                                  const float* __restrict__ delta,
                                                  const float* __restrict__ xdbl,
                                                  const float* __restrict__ A_log,
                                                  float* __restrict__ hend,
                                                  float* __restrict__ sumdt) {
    int d = blockIdx.x * 256 + threadIdx.x;  // 0..1535
    int c = blockIdx.y;                      // 0..NCHUNK-1
    int b = blockIdx.z;                      // 0..1
    float Ac2[16];
    const float4* Arow = (const float4*)(A_log + (size_t)d * DST);
#pragma unroll
    for (int q = 0; q < 4; ++q) {
        float4 a = Arow[q];
        Ac2[q * 4 + 0] = -__expf(a.x) * LOG2E;
        Ac2[q * 4 + 1] = -__expf(a.y) * LOG2E;
        Ac2[q * 4 + 2] = -__expf(a.z) * LOG2E;
        Ac2[q * 4 + 3] = -__expf(a.w) * LOG2E;
    }
    int l0 = c * CHUNK;
    const float* db = delta + ((size_t)b * LSEQ + l0) * DIN + d;
    const ushort* ub = u + ((size_t)b * LSEQ + l0) * DIN + d;
    const float* xB0 = xdbl + ((size_t)b * LSEQ + l0) * 80 + DTR;
    float h[16];
#pragma unroll
    for (int s = 0; s < 16; ++s) h[s] = 0.f;
    float sdt = 0.f;
#pragma unroll 2
    for (int l = 0; l < CHUNK; ++l) {
        float dt = db[(size_t)l * DIN];
        float uu = bf2f(ub[(size_t)l * DIN]);
        sdt += dt;
        float dtu = dt * uu;
        const float4* xB = (const float4*)(xB0 + l * 80);
        float4 b0 = xB[0], b1 = xB[1], b2 = xB[2], b3 = xB[3];
        float bv[16] = {b0.x, b0.y, b0.z, b0.w, b1.x, b1.y, b1.z, b1.w,
                        b2.x, b2.y, b2.z, b2.w, b3.x, b3.y, b3.z, b3.w};
#pragma unroll
        for (int s = 0; s < 16; ++s)
            h[s] = h[s] * exp2f(dt * Ac2[s]) + dtu * bv[s];
    }
    size_t obase = (((size_t)c * B_SZ + b) * DIN + d) * DST;
    float4* ho = (float4*)(hend + obase);
#pragma unroll
    for (int q = 0; q < 4; ++q)
        ho[q] = make_float4(h[q * 4 + 0], h[q * 4 + 1], h[q * 4 + 2], h[q * 4 + 3]);
    sumdt[((size_t)c * B_SZ + b) * DIN + d] = sdt;
}

// Pass B: thread = (b*DIN+d)*16+s; serial combine over chunks, P from sumdt.
__global__ __launch_bounds__(256) void scan_partB(const float* __restrict__ hend,
                                                  const float* __restrict__ sumdt,
                                                  const float* __restrict__ A_log,
                                                  float* __restrict__ Hinit) {
    int tid = blockIdx.x * 256 + threadIdx.x;  // 0..49151
    int s = tid & 15;
    int bd = tid >> 4;       // b*DIN+d
    int d = bd % DIN;
    float Ac2 = -__expf(A_log[(size_t)d * DST + s]) * LOG2E;
    float H = 0.f;
#pragma unroll 4
    for (int c = 0; c < NCHUNK; ++c) {
        size_t idx = (size_t)c * (B_SZ * DIN * DST) + tid;
        Hinit[idx] = H;
        float P = exp2f(sumdt[(size_t)c * (B_SZ * DIN) + bd] * Ac2);
        H = P * H + hend[idx];
    }
}

__global__ __launch_bounds__(256) void scan_partC(const ushort* __restrict__ u,
                                                  const float* __restrict__ delta,
                                                  const float* __restrict__ xdbl,
                                                  const ushort* __restrict__ xz,
                                                  const float* __restrict__ A_log,
                                                  const float* __restrict__ Dskip,
                                                  const float* __restrict__ Hinit,
                                                  ushort* __restrict__ yg) {
    int d = blockIdx.x * 256 + threadIdx.x;
    int c = blockIdx.y;
    int b = blockIdx.z;
    float Ac2[16];
    const float4* Arow = (const float4*)(A_log + (size_t)d * DST);
#pragma unroll
    for (int q = 0; q < 4; ++q) {
        float4 a = Arow[q];
        Ac2[q * 4 + 0] = -__expf(a.x) * LOG2E;
        Ac2[q * 4 + 1] = -__expf(a.y) * LOG2E;
        Ac2[q * 4 + 2] = -__expf(a.z) * LOG2E;
        Ac2[q * 4 + 3] = -__expf(a.w) * LOG2E;
    }
    float Dv = Dskip[d];
    int l0 = c * CHUNK;
    const float* db = delta + ((size_t)b * LSEQ + l0) * DIN + d;
    const ushort* ub = u + ((size_t)b * LSEQ + l0) * DIN + d;
    const float* xB0 = xdbl + ((size_t)b * LSEQ + l0) * 80 + DTR;
    const ushort* zb = xz + ((size_t)b * LSEQ + l0) * (2 * DIN) + DIN + d;
    ushort* yb = yg + ((size_t)b * LSEQ + l0) * DIN + d;
    float h[16];
    const float4* hi = (const float4*)(Hinit + (((size_t)c * B_SZ + b) * DIN + d) * DST);
#pragma unroll
    for (int q = 0; q < 4; ++q) {
        float4 v = hi[q];
        h[q * 4 + 0] = v.x; h[q * 4 + 1] = v.y; h[q * 4 + 2] = v.z; h[q * 4 + 3] = v.w;
    }
#pragma unroll 2
    for (int l = 0; l < CHUNK; ++l) {
        float dt = db[(size_t)l * DIN];
        float uu = bf2f(ub[(size_t)l * DIN]);
        float dtu = dt * uu;
        const float4* xB = (const float4*)(xB0 + l * 80);
        float4 b0 = xB[0], b1 = xB[1], b2 = xB[2], b3 = xB[3];
        float4 c0 = xB[4], c1 = xB[5], c2 = xB[6], c3 = xB[7];
        float bv[16] = {b0.x, b0.y, b0.z, b0.w, b1.x, b1.y, b1.z, b1.w,
                        b2.x, b2.y, b2.z, b2.w, b3.x, b3.y, b3.z, b3.w};
        float cv[16] = {c0.x, c0.y, c0.z, c0.w, c1.x, c1.y, c1.z, c1.w,
                        c2.x, c2.y, c2.z, c2.w, c3.x, c3.y, c3.z, c3.w};
        float acc = 0.f;
#pragma unroll
        for (int s = 0; s < 16; ++s) {
            h[s] = h[s] * exp2f(dt * Ac2[s]) + dtu * bv[s];
            acc = fmaf(h[s], cv[s], acc);
        }
        float z = bf2f(zb[(size_t)l * (2 * DIN)]);
        float y = acc + uu * Dv;
        yb[(size_t)l * DIN] = f2bf(y * (z * sigmoidf_(z)));
    }
}

extern "C" void kernel_launch(void* const* d_in, const int* in_sizes, int n_in,
                              void* d_out, int out_size, void* d_ws, size_t ws_size,
                              hipStream_t stream) {
    const float* x    = (const float*)d_in[0];
    const float* lng  = (const float*)d_in[1];
    const float* lnb  = (const float*)d_in[2];
    const float* win  = (const float*)d_in[3];
    const float* cw   = (const float*)d_in[4];
    const float* cb   = (const float*)d_in[5];
    const float* wxp  = (const float*)d_in[6];
    const float* wdt  = (const float*)d_in[7];
    const float* bdt  = (const float*)d_in[8];
    const float* alog = (const float*)d_in[9];
    const float* dsk  = (const float*)d_in[10];
    const float* wout = (const float*)d_in[11];
    float* out = (float*)d_out;

    char* wsb = (char*)d_ws;
    size_t off = 0;
    auto alloc = [&](size_t bytes) { char* p = wsb + off; off += (bytes + 255) & ~255ull; return p; };
    ushort* xz_b   = (ushort*)alloc((size_t)NROWS * 2 * DIN * 2);  // 25.2 MB
    ushort* u_b    = (ushort*)alloc((size_t)NROWS * DIN * 2);      // 12.6 MB
    float*  delta  = (float*) alloc((size_t)NROWS * DIN * 4);      // 25.2 MB (early: xpart)
    float*  xdbl   = (float*) alloc((size_t)NROWS * 80 * 4);       // 1.3 MB
    ushort* yg_b   = (ushort*)alloc((size_t)NROWS * DIN * 2);      // 12.6 MB
    char*   R      = alloc(52430848);                              // overlay region
    ushort* wout_b = (ushort*)alloc((size_t)DIMC * DIN * 2);       // 2.36 MB
    ushort* wxp_b  = (ushort*)alloc((size_t)96 * DIN * 2);         // 0.29 MB
    ushort* wdt_b  = (ushort*)alloc((size_t)DIN * 64 * 2);         // 0.20 MB
    ushort* xpad_b = (ushort*)alloc((size_t)NROWS * 64 * 2);       // 0.52 MB
    // overlay 1 (pre-in_proj): hln + win_b
    ushort* hln_b  = (ushort*)R;                 // 6.29 MB
    ushort* win_b  = (ushort*)(R + 6291456);     // 4.72 MB
    // overlay 2 (scan): hend + Hinit + sumdt
    float*  hend   = (float*)R;                        // 25.2 MB
    float*  Hinit  = (float*)(R + 25165824);           // 25.2 MB
    float*  sumdt  = (float*)(R + 50331648);           // 1.6 MB
    float*  xpart  = delta;                      // 8 * 4096*80*4 = 10.5 MB

    cvt_all<<<(NW1 + NW2 + NW3 + NW4 + 255) / 256, 256, 0, stream>>>(
        win, wout, wxp, wdt, win_b, wout_b, wxp_b, wdt_b);
    ln_kernel<<<NROWS, 256, 0, stream>>>(x, lng, lnb, hln_b);
    gemm_mfma<128, 128, 0><<<dim3(24, 32, 1), 256, 0, stream>>>(hln_b, DIMC, win_b, nullptr, xz_b, DIMC, 2 * DIN, DIMC);
    conv_silu<<<dim3(6, NROWS), 256, 0, stream>>>(xz_b, cw, cb, u_b);
    gemm_mfma<128, 96, 2><<<dim3(1, 32, 8), 256, 0, stream>>>(u_b, DIN, wxp_b, nullptr, xpart, DIN, 80, DIN / 8);
    xproj_reduce<<<1280, 256, 0, stream>>>(xpart, xdbl, xpad_b);
    gemm_mfma<128, 128, 3><<<dim3(12, 32, 1), 256, 0, stream>>>(xpad_b, 64, wdt_b, bdt, delta, 64, DIN, 64);
    scan_partA<<<dim3(6, NCHUNK, B_SZ), 256, 0, stream>>>(u_b, delta, xdbl, alog, hend, sumdt);
    scan_partB<<<192, 256, 0, stream>>>(hend, sumdt, alog, Hinit);
    scan_partC<<<dim3(6, NCHUNK, B_SZ), 256, 0, stream>>>(u_b, delta, xdbl, xz_b, alog, dsk, Hinit, yg_b);
    gemm_mfma<128, 64, 1><<<dim3(12, 32, 1), 256, 0, stream>>>(yg_b, DIN, wout_b, x, out, DIN, DIMC, DIN);
}